// Round 3
// baseline (281.381 us; speedup 1.0000x reference)
//
#include <hip/hip_runtime.h>

#define D 128
#define KN 32

typedef __bf16 bf16x8 __attribute__((ext_vector_type(8)));
typedef float f32x4 __attribute__((ext_vector_type(4)));

// --- f32 -> bf16 (RNE) packing helpers -------------------------------------
__device__ __forceinline__ unsigned bfpack2(float a, float b) {
  unsigned ua = __float_as_uint(a), ub = __float_as_uint(b);
  ua += 0x7FFFu + ((ua >> 16) & 1u);
  ub += 0x7FFFu + ((ub >> 16) & 1u);
  return (ua >> 16) | (ub & 0xFFFF0000u);
}
__device__ __forceinline__ uint4 pack8(const float4& a, const float4& b) {
  uint4 r;
  r.x = bfpack2(a.x, a.y); r.y = bfpack2(a.z, a.w);
  r.z = bfpack2(b.x, b.y); r.w = bfpack2(b.z, b.w);
  return r;
}

// Stage 128x128 f32 -> bf16 LDS chunks: buf[row*16 + (slot ^ (row&7))] = cols slot*8..+7.
__device__ __forceinline__ void stage128(const float* __restrict__ src, int nrows,
                                         uint4* buf, int tid) {
  float4 v[4][2];
  #pragma unroll
  for (int i = 0; i < 4; ++i) {
    const int c = i * 512 + tid;
    const int row = c >> 4, slot = c & 15;
    if (row < nrows) {
      const float4* p = (const float4*)(src + (size_t)row * D + slot * 8);
      v[i][0] = p[0]; v[i][1] = p[1];
    } else {
      v[i][0] = make_float4(0.f, 0.f, 0.f, 0.f);
      v[i][1] = make_float4(0.f, 0.f, 0.f, 0.f);
    }
  }
  #pragma unroll
  for (int i = 0; i < 4; ++i) {
    const int c = i * 512 + tid;
    const int row = c >> 4, slot = c & 15;
    buf[row * 16 + (slot ^ (row & 7))] = pack8(v[i][0], v[i][1]);
  }
}

// base[r,e] = sum_d x[r,d]*Wx[e,d] + bx[e]+bn[e]+bw[e]  -> d_out  (unchanged from R2)
__global__ __launch_bounds__(512, 4) void base_mfma(
    const float* __restrict__ x, const float* __restrict__ Wx,
    const float* __restrict__ bx, const float* __restrict__ bn,
    const float* __restrict__ bw, float* __restrict__ out, int N)
{
  __shared__ uint4 Bb[2048];
  __shared__ uint4 Ab[2048];
  __shared__ float bvec[D];
  const int tid = threadIdx.x;

  stage128(Wx, 128, Bb, tid);
  if (tid < D) bvec[tid] = bx[tid] + bn[tid] + bw[tid];

  const int lane = tid & 63, li = lane & 15, g = lane >> 4;
  const int wv = tid >> 6, rq = wv >> 1, ch = wv & 1;
  const int ntiles = (N + 127) >> 7;

  for (int t = blockIdx.x; t < ntiles; t += gridDim.x) {
    const int r0t = t << 7;
    __syncthreads();
    stage128(x + (size_t)r0t * D, N - r0t, Ab, tid);
    __syncthreads();

    f32x4 acc[2][4];
    #pragma unroll
    for (int i = 0; i < 2; ++i)
      #pragma unroll
      for (int j = 0; j < 4; ++j) acc[i][j] = (f32x4){0.f, 0.f, 0.f, 0.f};

    #pragma unroll
    for (int kb = 0; kb < 4; ++kb) {
      const int slot = kb * 4 + g;
      const int r0 = rq * 32 + li, r1 = r0 + 16;
      const bf16x8 a0 = __builtin_bit_cast(bf16x8, Ab[r0 * 16 + (slot ^ (r0 & 7))]);
      const bf16x8 a1 = __builtin_bit_cast(bf16x8, Ab[r1 * 16 + (slot ^ (r1 & 7))]);
      #pragma unroll
      for (int ct = 0; ct < 4; ++ct) {
        const int e = ch * 64 + ct * 16 + li;
        const bf16x8 b = __builtin_bit_cast(bf16x8, Bb[e * 16 + (slot ^ (e & 7))]);
        acc[0][ct] = __builtin_amdgcn_mfma_f32_16x16x32_bf16(a0, b, acc[0][ct], 0, 0, 0);
        acc[1][ct] = __builtin_amdgcn_mfma_f32_16x16x32_bf16(a1, b, acc[1][ct], 0, 0, 0);
      }
    }

    #pragma unroll
    for (int rt = 0; rt < 2; ++rt) {
      #pragma unroll
      for (int reg = 0; reg < 4; ++reg) {
        const int r = r0t + rq * 32 + rt * 16 + 4 * g + reg;
        if (r < N) {
          #pragma unroll
          for (int ct = 0; ct < 4; ++ct) {
            const int e = ch * 64 + ct * 16 + li;
            out[(size_t)r * D + e] = acc[rt][ct][reg] + bvec[e];
          }
        }
      }
    }
  }
}

// Fused pipelined kernel: 2 nodes (64 rows) per iter; x_nb tile kept in LDS as
// f32 (single pass from HBM); A-frags packed f32->bf16 at read; epilogue reads
// the same f32 tile. Software pipelined: next tile's global loads issued at
// iteration top, LDS-written after the epilogue.
__global__ __launch_bounds__(512, 4) void gnn_mfma(
    const float* __restrict__ x_nb, const float* __restrict__ weight,
    const float* __restrict__ Wn, const float* __restrict__ Ww,
    const float* __restrict__ Wl, float* __restrict__ out, int N)
{
  __shared__ uint4 Bb[2048];        // 32 KB: Wn bf16, chunk (row e)*16 + (slot ^ (e&7))
  __shared__ f32x4 Axf[2048];       // 32 KB: x_nb f32 [64 rows][32 slots], slot ^ (row&7)
  __shared__ float basel[2 * D];
  __shared__ float wwl[D], wll[D];
  __shared__ float wgt[2 * KN];
  __shared__ float spart[4][2][KN];
  __shared__ float attnl[2 * KN];

  const int tid = threadIdx.x;
  stage128(Wn, 128, Bb, tid);
  if (tid < D) { wwl[tid] = Ww[tid]; wll[tid] = Wl[tid]; }

  const int lane = tid & 63, li = lane & 15, g = lane >> 4;
  const int wv = tid >> 6, rq = wv >> 2, ch = wv & 3;   // node = rq (2), 32-col quarter = ch (4)
  const int ntiles = N >> 1;                             // 25000 (N even)

  float4 v[4]; float basev = 0.f, wgtv = 0.f;

  int t = blockIdx.x;
  {  // prologue: load + stage tile t
    const float* src = x_nb + (size_t)(2 * t) * KN * D;
    #pragma unroll
    for (int i = 0; i < 4; ++i) v[i] = *(const float4*)(src + (size_t)(i * 512 + tid) * 4);
    if (tid < 2 * D) basev = out[(size_t)(2 * t) * D + tid];
    if (tid < 2 * KN) wgtv = weight[(size_t)(2 * t) * KN + tid];
    #pragma unroll
    for (int i = 0; i < 4; ++i) {
      const int c = i * 512 + tid, row = c >> 5, sl = c & 31;
      Axf[row * 32 + (sl ^ (row & 7))] = __builtin_bit_cast(f32x4, v[i]);
    }
    if (tid < 2 * D) basel[tid] = basev;
    if (tid < 2 * KN) wgt[tid] = wgtv;
  }
  __syncthreads();

  for (; t < ntiles; t += gridDim.x) {
    const int tn = t + gridDim.x;
    const bool have_next = (tn < ntiles);
    if (have_next) {  // prefetch issue (T14): consumed only at stage-write below
      const float* src = x_nb + (size_t)(2 * tn) * KN * D;
      #pragma unroll
      for (int i = 0; i < 4; ++i) v[i] = *(const float4*)(src + (size_t)(i * 512 + tid) * 4);
      if (tid < 2 * D) basev = out[(size_t)(2 * tn) * D + tid];
      if (tid < 2 * KN) wgtv = weight[(size_t)(2 * tn) * KN + tid];
    }

    // --- MFMA: rows rq*32..+31, cols ch*32..+31; A packed f32->bf16 at read ---
    f32x4 acc[2][2];
    #pragma unroll
    for (int i = 0; i < 2; ++i)
      #pragma unroll
      for (int j = 0; j < 2; ++j) acc[i][j] = (f32x4){0.f, 0.f, 0.f, 0.f};

    #pragma unroll
    for (int kb = 0; kb < 4; ++kb) {
      bf16x8 a[2];
      #pragma unroll
      for (int rt = 0; rt < 2; ++rt) {
        const int r = rq * 32 + rt * 16 + li;
        const int s0 = kb * 8 + 2 * g;
        const f32x4 f0 = Axf[r * 32 + (s0 ^ (r & 7))];
        const f32x4 f1 = Axf[r * 32 + ((s0 + 1) ^ (r & 7))];
        uint4 u;
        u.x = bfpack2(f0[0], f0[1]); u.y = bfpack2(f0[2], f0[3]);
        u.z = bfpack2(f1[0], f1[1]); u.w = bfpack2(f1[2], f1[3]);
        a[rt] = __builtin_bit_cast(bf16x8, u);
      }
      const int slot = kb * 4 + g;
      #pragma unroll
      for (int ct = 0; ct < 2; ++ct) {
        const int e = ch * 32 + ct * 16 + li;
        const bf16x8 b = __builtin_bit_cast(bf16x8, Bb[e * 16 + (slot ^ (e & 7))]);
        acc[0][ct] = __builtin_amdgcn_mfma_f32_16x16x32_bf16(a[0], b, acc[0][ct], 0, 0, 0);
        acc[1][ct] = __builtin_amdgcn_mfma_f32_16x16x32_bf16(a[1], b, acc[1][ct], 0, 0, 0);
      }
    }

    // --- scores: s[k] = sum_e leaky(n_s + base + w*Ww) * Wl ---
    float bvv[2], wwv[2], wlv[2];
    #pragma unroll
    for (int ct = 0; ct < 2; ++ct) {
      const int e = ch * 32 + ct * 16 + li;
      bvv[ct] = basel[rq * D + e];
      wwv[ct] = wwl[e];
      wlv[ct] = wll[e];
    }
    #pragma unroll
    for (int rt = 0; rt < 2; ++rt) {
      #pragma unroll
      for (int reg = 0; reg < 4; ++reg) {
        const int k = rt * 16 + 4 * g + reg;
        const float wk = wgt[rq * KN + k];
        float p = 0.f;
        #pragma unroll
        for (int ct = 0; ct < 2; ++ct) {
          float h = acc[rt][ct][reg] + bvv[ct] + wk * wwv[ct];
          h = fmaxf(h, 0.1f * h);
          p = fmaf(h, wlv[ct], p);
        }
        p += __shfl_xor(p, 1);
        p += __shfl_xor(p, 2);
        p += __shfl_xor(p, 4);
        p += __shfl_xor(p, 8);
        if (li == 0) spart[ch][rq][k] = p;
      }
    }
    __syncthreads();

    // --- softmax over K=32 per node ---
    if (tid < 64) {
      const int node = tid >> 5, k = tid & 31;
      const float s = spart[0][node][k] + spart[1][node][k]
                    + spart[2][node][k] + spart[3][node][k];
      float mx = s;
      #pragma unroll
      for (int m = 16; m >= 1; m >>= 1) mx = fmaxf(mx, __shfl_xor(mx, m));
      const float pe = __expf(s - mx);
      float sum = pe;
      #pragma unroll
      for (int m = 16; m >= 1; m >>= 1) sum += __shfl_xor(sum, m);
      attnl[node * KN + k] = pe / sum;
    }
    __syncthreads();

    // --- epilogue: out[n,c] = sum_k attn[k] * x_nb_f32_lds[k][c] ---
    if (tid < 256) {
      const int node = tid >> 7, c = tid & 127;
      const int s = c >> 2, cc = c & 3;
      float o = 0.f;
      #pragma unroll
      for (int k = 0; k < KN; ++k) {
        const int r = node * KN + k;
        o = fmaf(attnl[node * KN + k], Axf[r * 32 + (s ^ (r & 7))][cc], o);
      }
      out[(size_t)(2 * t + node) * D + c] = o;
    }
    __syncthreads();  // all Axf/attnl reads complete

    if (have_next) {  // stage-write next tile (vmcnt wait lands here)
      #pragma unroll
      for (int i = 0; i < 4; ++i) {
        const int c = i * 512 + tid, row = c >> 5, sl = c & 31;
        Axf[row * 32 + (sl ^ (row & 7))] = __builtin_bit_cast(f32x4, v[i]);
      }
      if (tid < 2 * D) basel[tid] = basev;
      if (tid < 2 * KN) wgt[tid] = wgtv;
    }
    __syncthreads();
  }
}

extern "C" void kernel_launch(void* const* d_in, const int* in_sizes, int n_in,
                              void* d_out, int out_size, void* d_ws, size_t ws_size,
                              hipStream_t stream) {
  const float* x      = (const float*)d_in[0];
  const float* x_nb   = (const float*)d_in[1];
  const float* weight = (const float*)d_in[2];
  const float* Wx     = (const float*)d_in[3];
  const float* bx     = (const float*)d_in[4];
  const float* Wn     = (const float*)d_in[5];
  const float* bn     = (const float*)d_in[6];
  const float* Ww     = (const float*)d_in[7];
  const float* bw     = (const float*)d_in[8];
  const float* Wl     = (const float*)d_in[9];
  float* out = (float*)d_out;
  const int N = in_sizes[0] / D;  // 50000

  base_mfma<<<dim3(391), dim3(512), 0, stream>>>(x, Wx, bx, bn, bw, out, N);
  gnn_mfma<<<dim3(512), dim3(512), 0, stream>>>(x_nb, weight, Wn, Ww, Wl, out, N);
}